// Round 3
// baseline (542.335 us; speedup 1.0000x reference)
//
#include <hip/hip_runtime.h>

// LeNet-5 forward, fully fused. ROUND 16: EXACT RESIDENCY + DEEP PREFETCH.
//
// Rocprof r15 post-mortem (96us, worse than r14's 85):
//  * WRITE_SIZE 8.4MB + FETCH +3.6MB = scratch spill: 7 m-tiles/wave of acc
//    under the 128-reg cap of __launch_bounds__(128,4). VGPR_Count=64 is the
//    arch half; unified VGPR+AGPR hit the cap.
//  * SQ_LDS_BANK_CONFLICT x35: ROW1=228 -> 114 words == 18 == 6*3 (mod 32),
//    a multiple of the 6-word channel stride -> rows alias on the bank
//    lattice for conv2's b64 A-reads. ROW1=248 (==28 mod 32) de-aliases.
//  * dist-1 weight prefetch covers ~68cyc of MFMA vs ~250cyc L2 latency:
//    every K-step stalls ~180cyc on vmcnt. Dominant stall.
//
// Round-16:
//  * __launch_bounds__(128, 2): 256-reg cap. No spill; room for deep rings.
//  * grid = B/4 = 1024 blocks (2 waves, 1 image each, 2 images sequentially):
//    4 blocks/CU exactly resident (25.2 KB LDS), zero straggler round.
//  * ROW1 back to 248 (row pads [228,248) zeroed per image).
//  * distance-3 weight prefetch rings (conv1 per-kc, conv2/conv3 per-it)
//    + distance-1 A-fragment double buffer: ~250cyc of cover per load.
//  * zero __syncthreads (wave owns image end-to-end; h1->h2->h3 overlay in
//    own region; per-wave in-order LDS). setprio(1) around MFMA bursts.
//
// Layouts: conv1 as GEMM (row-only im2col), banded weights K=288, N=192.
//   per-wave region (6312 elems): h1 bf16 19x248 ([x*12+c]) at [0,4712),
//   xbf[2] bf16 800 each at [4712,5512),[5512,6312) (tails zeroed);
//   h2 bf16 10x248 ([x*20+c]) overlays h1; h3 fp32 720 overlays h1.
//   All K-padding baked into pre-packed weights (zeros).

typedef short s16x4 __attribute__((ext_vector_type(4)));
typedef short s16x8 __attribute__((ext_vector_type(8)));
typedef float f32x4 __attribute__((ext_vector_type(4)));

#define ROW1 248
#define ROW2 248
#define H1SZ 4712           // 19*248
#define XBSZ 800
#define IMSZ 6312           // H1SZ + 2*XBSZ
#define SM_ELEMS 12624      // 2*IMSZ

static __device__ __forceinline__ unsigned short f2bf(float f) {
    union { float f; unsigned int u; } v; v.f = f;
    unsigned int u = v.u;
    unsigned int r = (u + 0x7fffu + ((u >> 16) & 1u)) >> 16;   // RNE
    return (unsigned short)r;
}

static __device__ __forceinline__ s16x8 cat8(s16x4 lo, s16x4 hi) {
    return __builtin_shufflevector(lo, hi, 0, 1, 2, 3, 4, 5, 6, 7);
}

// ---- weight prep (unchanged layouts) --------------------------------------
// wbuf ushort: [0,40960) conv2 B-frags, [40960,61440) conv3 B-frags,
//              [61440,116736) conv1 banded B-frags (wband).
// 16x16x32 B-frag convention: n = nt*16 + (lane&15), k = kc*32 + quad*8 + t.
__global__ __launch_bounds__(256) void wprep_k(const float* __restrict__ w1,
                                               const float* __restrict__ w2,
                                               const float* __restrict__ w3,
                                               unsigned short* __restrict__ wbuf) {
    int e = blockIdx.x * 256 + threadIdx.x;
    if (e < 40960) {                       // conv2: j=k/12, c=k%12
        int t = e & 7, lane = (e >> 3) & 63, nt = (e >> 9) & 1;
        int ck = (e >> 10) & 3, i = e >> 12;
        int k = ck * 32 + ((lane >> 4) & 3) * 8 + t;
        int o = nt * 16 + (lane & 15);
        int j = k / 12, c = k % 12;
        float val = (j < 10 && c < 10 && o < 20) ? w2[o * 1000 + c * 100 + i * 10 + j] : 0.f;
        wbuf[e] = f2bf(val);
    } else if (e < 61440) {                // conv3: j=k/20, c=k%20
        int e2 = e - 40960;
        int t = e2 & 7, lane = (e2 >> 3) & 63, nt = (e2 >> 9) & 1;
        int ck = (e2 >> 10) & 3, i = e2 >> 12;
        int k = ck * 32 + ((lane >> 4) & 3) * 8 + t;
        int o = nt * 16 + (lane & 15);
        int j = k / 20, c = k % 20;
        float val = (j < 5 && o < 20) ? w3[o * 500 + c * 25 + i * 5 + j] : 0.f;
        wbuf[e] = f2bf(val);
    } else {                               // conv1 band: [nt(12)][kc(9)][lane][t]
        int e2 = e - 61440;                // < 55296
        int t = e2 & 7, lane = (e2 >> 3) & 63;
        int kc = (e2 >> 9) % 9, nt = (e2 >> 9) / 9;
        int n = nt * 16 + (lane & 15);
        int k = kc * 32 + ((lane >> 4) & 3) * 8 + t;
        float val = 0.f;
        if (n < 190 && k < 280) {
            int ox = n / 10, o = n - ox * 10;
            int i = k / 28, xc = k - i * 28;
            int j = xc - ox;
            if (j >= 0 && j < 10) val = w1[o * 100 + i * 10 + j];
        }
        wbuf[61440 + e2] = f2bf(val);
    }
}

// --------------------------- the fused kernel ------------------------------
__global__ __launch_bounds__(128, 2) void fused_k(const float* __restrict__ x,
                                                  const float* __restrict__ b1,
                                                  const unsigned short* __restrict__ wbuf2,
                                                  const unsigned short* __restrict__ wbuf3,
                                                  const unsigned short* __restrict__ wband,
                                                  const float* __restrict__ b2,
                                                  const float* __restrict__ b3,
                                                  const float* __restrict__ wf,
                                                  const float* __restrict__ bf,
                                                  float* __restrict__ out,
                                                  int half) {
    __shared__ __align__(16) unsigned short sm16[SM_ELEMS];

    const int tid = threadIdx.x;
    const int wave = tid >> 6, lane = tid & 63;
    const int quad = lane >> 4, lm = lane & 15;
    const int img0 = blockIdx.x * 2 + wave;            // + s*half

    unsigned short* h1w = sm16 + wave * IMSZ;          // [0,4712) own region
    unsigned short* xb2 = h1w + H1SZ;                  // [2][800]

    // ---- stage BOTH images as bf16 up front; zero xbf tails ---------------
#pragma unroll
    for (int s2 = 0; s2 < 2; ++s2) {
        const float4* src = (const float4*)(x + (size_t)(img0 + s2 * half) * 784);
        unsigned short* dst = xb2 + s2 * XBSZ;
        for (int k = lane; k < 196; k += 64) {
            float4 v = src[k];
            s16x4 p = { (short)f2bf(v.x), (short)f2bf(v.y),
                        (short)f2bf(v.z), (short)f2bf(v.w) };
            *(s16x4*)(dst + k * 4) = p;
        }
    }
    if (lane < 32) xb2[(lane >> 4) * XBSZ + 784 + (lane & 15)] = 0;

#pragma unroll 1
    for (int s = 0; s < 2; ++s) {
        const unsigned short* xbfw = xb2 + s * XBSZ;
        const int img = img0 + s * half;

        // ---- zero h1 row pads + c-pads (re-done per image: h3 clobbers) ---
        for (int e = lane; e < 95; e += 64) {          // row pads [228,248) x 19
            int row = e / 5, seg = e - row * 5;
            *(s16x4*)(h1w + row * ROW1 + 228 + seg * 4) = (s16x4){0, 0, 0, 0};
        }
        for (int e = lane; e < 361; e += 64) {         // c-pads (oy,ox,[10,12))
            int oy = e / 19, ox = e - oy * 19;
            *(unsigned int*)(h1w + oy * ROW1 + ox * 12 + 10) = 0u;
        }

        // ---- conv1 MFMA  M=32(19), N=192(190), K=288(280) -----------------
        // 12 nt tiles in 2 passes of 6; weight ring distance-3 over kc.
        {
            int ab0 = lm * 28 + quad * 8;
            int r1 = lm + 16; if (r1 > 18) r1 = 18;    // clamp pad rows
            int ab1 = r1 * 28 + quad * 8;
            const unsigned short* wb = wband + lane * 8;
#pragma unroll
            for (int g = 0; g < 2; ++g) {
                f32x4 acc1[6][2] = {};
                s16x8 wr[4][6];
#pragma unroll
                for (int d = 0; d < 3; ++d)            // prime kc=0,1,2
#pragma unroll
                    for (int q = 0; q < 6; ++q)
                        wr[d][q] = *(const s16x8*)(wb + (((g * 6 + q) * 9) + d) * 512);
#pragma unroll
                for (int kc = 0; kc < 9; ++kc) {
                    if (kc < 6) {                      // prefetch kc+3
#pragma unroll
                        for (int q = 0; q < 6; ++q)
                            wr[(kc + 3) & 3][q] =
                                *(const s16x8*)(wb + (((g * 6 + q) * 9) + kc + 3) * 512);
                    }
                    s16x8 a0 = cat8(*(const s16x4*)(xbfw + ab0 + kc * 32),
                                    *(const s16x4*)(xbfw + ab0 + kc * 32 + 4));
                    s16x8 a1 = cat8(*(const s16x4*)(xbfw + ab1 + kc * 32),
                                    *(const s16x4*)(xbfw + ab1 + kc * 32 + 4));
                    __builtin_amdgcn_s_setprio(1);
#pragma unroll
                    for (int q = 0; q < 6; ++q) {
                        acc1[q][0] = __builtin_amdgcn_mfma_f32_16x16x32_bf16(a0, wr[kc & 3][q], acc1[q][0], 0, 0, 0);
                        acc1[q][1] = __builtin_amdgcn_mfma_f32_16x16x32_bf16(a1, wr[kc & 3][q], acc1[q][1], 0, 0, 0);
                    }
                    __builtin_amdgcn_s_setprio(0);
                }
#pragma unroll
                for (int q = 0; q < 6; ++q) {
                    int n = (g * 6 + q) * 16 + lm;
                    if (n < 190) {
                        int ox = n / 10, o = n - ox * 10;
                        float bias = b1[o];
#pragma unroll
                        for (int mt = 0; mt < 2; ++mt) {
#pragma unroll
                            for (int r = 0; r < 4; ++r) {
                                int oy = mt * 16 + quad * 4 + r;
                                if (oy < 19)
                                    h1w[oy * ROW1 + ox * 12 + o] =
                                        f2bf(fmaxf(acc1[q][mt][r] + bias, 0.f));
                            }
                        }
                    }
                }
            }
        }

        // ---- conv2 MFMA  M=112(100), N=32(20), K=1280(1000) ---------------
        // 7 m-tiles; weight ring distance-3; A-frag double buffer dist-1.
        int abase[7];
#pragma unroll
        for (int mt = 0; mt < 7; ++mt) {
            int m = mt * 16 + lm; if (m > 99) m = 99;
            int y = m / 10, xx = m - 10 * y;
            abase[mt] = y * ROW1 + xx * 12 + quad * 8;
        }
        f32x4 acc[7][2] = {};
        {
            const unsigned short* wptr = wbuf2 + lane * 8;
            s16x8 w0r[4], w1r[4];
#pragma unroll
            for (int d = 0; d < 3; ++d) {
                w0r[d] = *(const s16x8*)(wptr + d * 1024);
                w1r[d] = *(const s16x8*)(wptr + d * 1024 + 512);
            }
            s16x8 afc[7], afn[7];
#pragma unroll
            for (int mt = 0; mt < 7; ++mt)
                afc[mt] = cat8(*(const s16x4*)(h1w + abase[mt]),
                               *(const s16x4*)(h1w + abase[mt] + 4));
#pragma unroll
            for (int it = 0; it < 40; ++it) {
                if (it < 37) {                         // prefetch it+3
                    w0r[(it + 3) & 3] = *(const s16x8*)(wptr + (it + 3) * 1024);
                    w1r[(it + 3) & 3] = *(const s16x8*)(wptr + (it + 3) * 1024 + 512);
                }
                if (it < 39) {                         // A dist-1
                    const unsigned short* sbn = h1w + ((it + 1) >> 2) * ROW1 + ((it + 1) & 3) * 32;
#pragma unroll
                    for (int mt = 0; mt < 7; ++mt)
                        afn[mt] = cat8(*(const s16x4*)(sbn + abase[mt]),
                                       *(const s16x4*)(sbn + abase[mt] + 4));
                }
                __builtin_amdgcn_s_setprio(1);
#pragma unroll
                for (int mt = 0; mt < 7; ++mt) {
                    acc[mt][0] = __builtin_amdgcn_mfma_f32_16x16x32_bf16(afc[mt], w0r[it & 3], acc[mt][0], 0, 0, 0);
                    acc[mt][1] = __builtin_amdgcn_mfma_f32_16x16x32_bf16(afc[mt], w1r[it & 3], acc[mt][1], 0, 0, 0);
                }
                __builtin_amdgcn_s_setprio(0);
#pragma unroll
                for (int mt = 0; mt < 7; ++mt) afc[mt] = afn[mt];
            }
        }

        // ---- scatter conv2 -> h2 ([x*20+c], overlays own h1) --------------
        // h2 row pads [200,248) keep stale finite h1 data; weights there = 0.
        unsigned short* h2w = h1w;
#pragma unroll
        for (int mt = 0; mt < 7; ++mt) {
#pragma unroll
            for (int nt = 0; nt < 2; ++nt) {
                int o = nt * 16 + lm;
                if (o < 20) {
                    float bias = b2[o];
#pragma unroll
                    for (int r = 0; r < 4; ++r) {
                        int pos = mt * 16 + quad * 4 + r;
                        if (pos < 100) {
                            int y2 = pos / 10, x2 = pos - 10 * y2;
                            h2w[y2 * ROW2 + x2 * 20 + o] =
                                f2bf(fmaxf(acc[mt][nt][r] + bias, 0.f));
                        }
                    }
                }
            }
        }

        // ---- conv3 MFMA  M=48(36), N=32(20), K=640(500) -------------------
        int abase3[3];
#pragma unroll
        for (int mt = 0; mt < 3; ++mt) {
            int m = mt * 16 + lm; if (m > 35) m = 35;
            int oy = m / 6, ox = m - 6 * oy;
            abase3[mt] = oy * ROW2 + ox * 20 + quad * 8;
        }
        f32x4 acc3[3][2] = {};
        {
            const unsigned short* wptr = wbuf3 + lane * 8;
            s16x8 w0r[4], w1r[4];
#pragma unroll
            for (int d = 0; d < 3; ++d) {
                w0r[d] = *(const s16x8*)(wptr + d * 1024);
                w1r[d] = *(const s16x8*)(wptr + d * 1024 + 512);
            }
            s16x8 afc[3], afn[3];
#pragma unroll
            for (int mt = 0; mt < 3; ++mt)
                afc[mt] = cat8(*(const s16x4*)(h2w + abase3[mt]),
                               *(const s16x4*)(h2w + abase3[mt] + 4));
#pragma unroll
            for (int it = 0; it < 20; ++it) {
                if (it < 17) {                         // prefetch it+3
                    w0r[(it + 3) & 3] = *(const s16x8*)(wptr + (it + 3) * 1024);
                    w1r[(it + 3) & 3] = *(const s16x8*)(wptr + (it + 3) * 1024 + 512);
                }
                if (it < 19) {                         // A dist-1
                    const unsigned short* sbn = h2w + ((it + 1) >> 2) * ROW2 + ((it + 1) & 3) * 32;
#pragma unroll
                    for (int mt = 0; mt < 3; ++mt)
                        afn[mt] = cat8(*(const s16x4*)(sbn + abase3[mt]),
                                       *(const s16x4*)(sbn + abase3[mt] + 4));
                }
                __builtin_amdgcn_s_setprio(1);
#pragma unroll
                for (int mt = 0; mt < 3; ++mt) {
                    acc3[mt][0] = __builtin_amdgcn_mfma_f32_16x16x32_bf16(afc[mt], w0r[it & 3], acc3[mt][0], 0, 0, 0);
                    acc3[mt][1] = __builtin_amdgcn_mfma_f32_16x16x32_bf16(afc[mt], w1r[it & 3], acc3[mt][1], 0, 0, 0);
                }
                __builtin_amdgcn_s_setprio(0);
#pragma unroll
                for (int mt = 0; mt < 3; ++mt) afc[mt] = afn[mt];
            }
        }

        // ---- conv3 epilogue -> h3w[o*36+pos] (fp32, relu, overlays h1) ----
        float* h3w = (float*)h1w;
#pragma unroll
        for (int mt = 0; mt < 3; ++mt) {
#pragma unroll
            for (int nt = 0; nt < 2; ++nt) {
                int o = nt * 16 + lm;
                if (o < 20) {
                    float b3v = b3[o];
#pragma unroll
                    for (int r = 0; r < 4; ++r) {
                        int pos = mt * 16 + quad * 4 + r;
                        if (pos < 36)
                            h3w[o * 36 + pos] = fmaxf(acc3[mt][nt][r] + b3v, 0.f);
                    }
                }
            }
        }

        // ---- fc: coalesced global wf; single-wave reduce ------------------
        float part[10];
#pragma unroll
        for (int n = 0; n < 10; ++n) part[n] = 0.f;
#pragma unroll 2
        for (int t = 0; t < 11; ++t) {                 // k = 0..703
            int k = t * 64 + lane;
            float v = h3w[k];
#pragma unroll
            for (int n = 0; n < 10; ++n)
                part[n] = fmaf(v, wf[n * 720 + k], part[n]);
        }
        {                                              // tail k = 704..719
            int k = 704 + lane;
            if (lane < 16) {
                float v = h3w[k];
#pragma unroll
                for (int n = 0; n < 10; ++n)
                    part[n] = fmaf(v, wf[n * 720 + k], part[n]);
            }
        }
#pragma unroll
        for (int n = 0; n < 10; ++n) {
#pragma unroll
            for (int off = 32; off >= 1; off >>= 1)
                part[n] += __shfl_xor(part[n], off, 64);
        }
        if (lane == 0) {
            float* dst = out + (size_t)img * 10;
#pragma unroll
            for (int n = 0; n < 10; ++n) dst[n] = part[n] + bf[n];
        }
    }
}

extern "C" void kernel_launch(void* const* d_in, const int* in_sizes, int n_in,
                              void* d_out, int out_size, void* d_ws, size_t ws_size,
                              hipStream_t stream) {
    (void)n_in; (void)out_size; (void)ws_size;
    const float* x  = (const float*)d_in[0];
    const float* w1 = (const float*)d_in[1];
    const float* b1 = (const float*)d_in[2];
    const float* w2 = (const float*)d_in[3];
    const float* b2 = (const float*)d_in[4];
    const float* w3 = (const float*)d_in[5];
    const float* b3 = (const float*)d_in[6];
    const float* wf = (const float*)d_in[7];
    const float* bf = (const float*)d_in[8];
    float* out = (float*)d_out;

    const int B = in_sizes[0] / 784;                   // 4096
    const int half = B / 2;

    unsigned short* wbuf = (unsigned short*)d_ws;      // 116736 bf16 = 228 KB

    wprep_k<<<456, 256, 0, stream>>>(w1, w2, w3, wbuf);
    fused_k<<<B / 4, 128, 0, stream>>>(x, b1, wbuf, wbuf + 40960, wbuf + 61440,
                                       b2, b3, wf, bf, out, half);
}

// Round 4
// 156.646 us; speedup vs baseline: 3.4622x; 3.4622x over previous
//
#include <hip/hip_runtime.h>

// LeNet-5 forward, fully fused. ROUND 17: ZERO-BARRIER + EXACT RESIDENCY,
// NO xbf (conv1 A-frags straight from global), r14 register shape.
//
// Post-mortems driving this round:
//  r15 (96us): zero-barrier structure RAISED occupancy 26->41% but was
//    sabotaged by (a) ROW1=228 bank-conflict lattice (1.1e7 conflicts, 35x)
//    and (b) ~16-reg spill from afn[7] double-buffer (WRITE_SIZE 8.4MB).
//  r16 (478us): distance-3 rings cost ~100 VGPRs -> catastrophic spill
//    (455MB scratch). Prefetch depth is paid in registers; budget ~125.
//  r13 (85us, best): MFMA work/image = 896 x 4.85cyc -> 29us floor at 100%
//    MfmaUtil; measured 33%. Utilization, not traffic, is the lever.
//
// Round-17:
//  * r15's zero-barrier per-wave-owns-image dataflow (phase diversity ->
//    MFMA bursts overlap other waves' VALU/latency), with:
//  * ROW1=248 (conflict-free), conv2 single-buffered af[7] (r14's exact
//    no-spill register shape), conv1/conv2/conv3 dist-1 weight prefetch.
//  * xbf DELETED: conv1 A-frags load from global x (f32 dwordx4 pairs,
//    dist-1 prefetch, in-register RNE cvt to bf16). Image is 3KB -> L1.
//    OOB tail (k>=280: weight-zero) handled by clamping the elem offset.
//  * LDS = 2 x 4712 ushort = 18848 B -> 8 blocks/CU EXACTLY resident
//    (matches the 16-wave VGPR cap); grid 2048 = 8/CU, zero tail round.
//
// Layouts: conv1 as GEMM (row-only im2col), banded weights K=288, N=192.
//   h1 bf16 19x248 ([x*12+c], c-pads+row-pads zeroed) per wave;
//   h2 bf16 10x248 ([x*20+c]) overlays own h1; h3 fp32 720 overlays own h1.
//   All K-padding baked into pre-packed weights (zeros).

typedef short s16x4 __attribute__((ext_vector_type(4)));
typedef short s16x8 __attribute__((ext_vector_type(8)));
typedef float f32x4 __attribute__((ext_vector_type(4)));

#define ROW1 248
#define ROW2 248
#define H1SZ 4712           // 19*248
#define SM_ELEMS 9424       // 2*H1SZ -> 18848 B

static __device__ __forceinline__ unsigned short f2bf(float f) {
    union { float f; unsigned int u; } v; v.f = f;
    unsigned int u = v.u;
    unsigned int r = (u + 0x7fffu + ((u >> 16) & 1u)) >> 16;   // RNE
    return (unsigned short)r;
}

static __device__ __forceinline__ s16x8 cat8(s16x4 lo, s16x4 hi) {
    return __builtin_shufflevector(lo, hi, 0, 1, 2, 3, 4, 5, 6, 7);
}

static __device__ __forceinline__ s16x8 f2bf8(f32x4 a, f32x4 b) {
    s16x8 r;
    r[0] = (short)f2bf(a[0]); r[1] = (short)f2bf(a[1]);
    r[2] = (short)f2bf(a[2]); r[3] = (short)f2bf(a[3]);
    r[4] = (short)f2bf(b[0]); r[5] = (short)f2bf(b[1]);
    r[6] = (short)f2bf(b[2]); r[7] = (short)f2bf(b[3]);
    return r;
}

// ---- weight prep (unchanged layouts) --------------------------------------
// wbuf ushort: [0,40960) conv2 B-frags, [40960,61440) conv3 B-frags,
//              [61440,116736) conv1 banded B-frags (wband).
// 16x16x32 B-frag convention: n = nt*16 + (lane&15), k = kc*32 + quad*8 + t.
__global__ __launch_bounds__(256) void wprep_k(const float* __restrict__ w1,
                                               const float* __restrict__ w2,
                                               const float* __restrict__ w3,
                                               unsigned short* __restrict__ wbuf) {
    int e = blockIdx.x * 256 + threadIdx.x;
    if (e < 40960) {                       // conv2: j=k/12, c=k%12
        int t = e & 7, lane = (e >> 3) & 63, nt = (e >> 9) & 1;
        int ck = (e >> 10) & 3, i = e >> 12;
        int k = ck * 32 + ((lane >> 4) & 3) * 8 + t;
        int o = nt * 16 + (lane & 15);
        int j = k / 12, c = k % 12;
        float val = (j < 10 && c < 10 && o < 20) ? w2[o * 1000 + c * 100 + i * 10 + j] : 0.f;
        wbuf[e] = f2bf(val);
    } else if (e < 61440) {                // conv3: j=k/20, c=k%20
        int e2 = e - 40960;
        int t = e2 & 7, lane = (e2 >> 3) & 63, nt = (e2 >> 9) & 1;
        int ck = (e2 >> 10) & 3, i = e2 >> 12;
        int k = ck * 32 + ((lane >> 4) & 3) * 8 + t;
        int o = nt * 16 + (lane & 15);
        int j = k / 20, c = k % 20;
        float val = (j < 5 && o < 20) ? w3[o * 500 + c * 25 + i * 5 + j] : 0.f;
        wbuf[e] = f2bf(val);
    } else {                               // conv1 band: [nt(12)][kc(9)][lane][t]
        int e2 = e - 61440;                // < 55296
        int t = e2 & 7, lane = (e2 >> 3) & 63;
        int kc = (e2 >> 9) % 9, nt = (e2 >> 9) / 9;
        int n = nt * 16 + (lane & 15);
        int k = kc * 32 + ((lane >> 4) & 3) * 8 + t;
        float val = 0.f;
        if (n < 190 && k < 280) {
            int ox = n / 10, o = n - ox * 10;
            int i = k / 28, xc = k - i * 28;
            int j = xc - ox;
            if (j >= 0 && j < 10) val = w1[o * 100 + i * 10 + j];
        }
        wbuf[61440 + e2] = f2bf(val);
    }
}

// --------------------------- the fused kernel ------------------------------
__global__ __launch_bounds__(128, 4) void fused_k(const float* __restrict__ x,
                                                  const float* __restrict__ b1,
                                                  const unsigned short* __restrict__ wbuf2,
                                                  const unsigned short* __restrict__ wbuf3,
                                                  const unsigned short* __restrict__ wband,
                                                  const float* __restrict__ b2,
                                                  const float* __restrict__ b3,
                                                  const float* __restrict__ wf,
                                                  const float* __restrict__ bf,
                                                  float* __restrict__ out) {
    __shared__ __align__(16) unsigned short sm16[SM_ELEMS];

    const int tid = threadIdx.x;
    const int wave = tid >> 6, lane = tid & 63;
    const int quad = lane >> 4, lm = lane & 15;
    const int img = blockIdx.x * 2 + wave;             // this wave's image

    unsigned short* h1w = sm16 + wave * H1SZ;          // own 4712-elem region

    // ---- zero h1 row pads + c-pads (before conv1 epilogue writes) ---------
    for (int e = lane; e < 95; e += 64) {              // row pads [228,248) x 19
        int row = e / 5, seg = e - row * 5;
        *(s16x4*)(h1w + row * ROW1 + 228 + seg * 4) = (s16x4){0, 0, 0, 0};
    }
    for (int e = lane; e < 361; e += 64) {             // c-pads (oy,ox,[10,12))
        int oy = e / 19, ox = e - oy * 19;
        *(unsigned int*)(h1w + oy * ROW1 + ox * 12 + 10) = 0u;
    }

    // ---- conv1 MFMA  M=32(19), N=192(190), K=288(280) ---------------------
    // A-frags from GLOBAL x (f32), dist-1 prefetch, in-reg cvt to bf16.
    // 12 nt tiles in 2 passes of 6; per-q dist-1 weight ring.
    {
        const float* xg = x + (size_t)img * 784;
        const int ab0 = lm * 28 + quad * 8;            // <= 444
        int r1 = lm + 16; if (r1 > 18) r1 = 18;        // clamp pad rows
        const int ab1 = r1 * 28 + quad * 8;            // <= 528
        const unsigned short* wb = wband + lane * 8;
#pragma unroll 1
        for (int g = 0; g < 2; ++g) {
            f32x4 acc1[6][2] = {};
            f32x4 c0a = *(const f32x4*)(xg + ab0);
            f32x4 c0b = *(const f32x4*)(xg + ab0 + 4);
            f32x4 c1a = *(const f32x4*)(xg + ab1);
            f32x4 c1b = *(const f32x4*)(xg + ab1 + 4);
#pragma unroll
            for (int kc = 0; kc < 9; ++kc) {
                f32x4 n0a, n0b, n1a, n1b;
                if (kc < 8) {                          // dist-1 A prefetch
                    int of0 = ab0 + (kc + 1) * 32;     // <= 700: in-bounds
                    int of1 = ab1 + (kc + 1) * 32;
                    if (of1 > 776) of1 = 776;          // k>=280 is weight-zero
                    n0a = *(const f32x4*)(xg + of0);
                    n0b = *(const f32x4*)(xg + of0 + 4);
                    n1a = *(const f32x4*)(xg + of1);
                    n1b = *(const f32x4*)(xg + of1 + 4);
                }
                s16x8 a0 = f2bf8(c0a, c0b);
                s16x8 a1 = f2bf8(c1a, c1b);
                s16x8 wq = *(const s16x8*)(wb + (((g * 6) * 9) + kc) * 512);
                __builtin_amdgcn_s_setprio(1);
#pragma unroll
                for (int q = 0; q < 6; ++q) {
                    s16x8 wn;
                    if (q < 5)                         // dist-1 weight ring
                        wn = *(const s16x8*)(wb + (((g * 6 + q + 1) * 9) + kc) * 512);
                    acc1[q][0] = __builtin_amdgcn_mfma_f32_16x16x32_bf16(a0, wq, acc1[q][0], 0, 0, 0);
                    acc1[q][1] = __builtin_amdgcn_mfma_f32_16x16x32_bf16(a1, wq, acc1[q][1], 0, 0, 0);
                    if (q < 5) wq = wn;
                }
                __builtin_amdgcn_s_setprio(0);
                c0a = n0a; c0b = n0b; c1a = n1a; c1b = n1b;
            }
#pragma unroll
            for (int q = 0; q < 6; ++q) {
                int n = (g * 6 + q) * 16 + lm;
                if (n < 190) {
                    int ox = n / 10, o = n - ox * 10;
                    float bias = b1[o];
#pragma unroll
                    for (int mt = 0; mt < 2; ++mt) {
#pragma unroll
                        for (int r = 0; r < 4; ++r) {
                            int oy = mt * 16 + quad * 4 + r;
                            if (oy < 19)
                                h1w[oy * ROW1 + ox * 12 + o] =
                                    f2bf(fmaxf(acc1[q][mt][r] + bias, 0.f));
                        }
                    }
                }
            }
        }
    }
    // no barrier: own region, per-wave in-order LDS.

    // ---- conv2 MFMA  M=112(100), N=32(20), K=1280(1000) -------------------
    // 7 m-tiles, single-buffered af[7] (r14's no-spill shape), dist-1 weights.
    int abase[7];
#pragma unroll
    for (int mt = 0; mt < 7; ++mt) {
        int m = mt * 16 + lm; if (m > 99) m = 99;
        int y = m / 10, xx = m - 10 * y;
        abase[mt] = y * ROW1 + xx * 12 + quad * 8;
    }
    f32x4 acc[7][2] = {};
    {
        const unsigned short* wptr = wbuf2 + lane * 8;
        s16x8 wc0 = *(const s16x8*)(wptr);
        s16x8 wc1 = *(const s16x8*)(wptr + 512);
#pragma unroll
        for (int it = 0; it < 40; ++it) {
            s16x8 wn0 = *(const s16x8*)(wptr + (it + 1) * 1024);   // tail->conv3 region
            s16x8 wn1 = *(const s16x8*)(wptr + (it + 1) * 1024 + 512);
            const unsigned short* sb = h1w + (it >> 2) * ROW1 + (it & 3) * 32;
            s16x8 af[7];
#pragma unroll
            for (int mt = 0; mt < 7; ++mt)
                af[mt] = cat8(*(const s16x4*)(sb + abase[mt]),
                              *(const s16x4*)(sb + abase[mt] + 4));
            __builtin_amdgcn_s_setprio(1);
#pragma unroll
            for (int mt = 0; mt < 7; ++mt) {
                acc[mt][0] = __builtin_amdgcn_mfma_f32_16x16x32_bf16(af[mt], wc0, acc[mt][0], 0, 0, 0);
                acc[mt][1] = __builtin_amdgcn_mfma_f32_16x16x32_bf16(af[mt], wc1, acc[mt][1], 0, 0, 0);
            }
            __builtin_amdgcn_s_setprio(0);
            wc0 = wn0; wc1 = wn1;
        }
    }

    // ---- scatter conv2 -> h2 ([x*20+c], overlays own h1) ------------------
    // h2 cols [200,248) keep stale finite h1 data; weights there are zero.
    unsigned short* h2w = h1w;
#pragma unroll
    for (int mt = 0; mt < 7; ++mt) {
#pragma unroll
        for (int nt = 0; nt < 2; ++nt) {
            int o = nt * 16 + lm;
            if (o < 20) {
                float bias = b2[o];
#pragma unroll
                for (int r = 0; r < 4; ++r) {
                    int pos = mt * 16 + quad * 4 + r;
                    if (pos < 100) {
                        int y2 = pos / 10, x2 = pos - 10 * y2;
                        h2w[y2 * ROW2 + x2 * 20 + o] =
                            f2bf(fmaxf(acc[mt][nt][r] + bias, 0.f));
                    }
                }
            }
        }
    }

    // ---- conv3 MFMA  M=48(36), N=32(20), K=640(500) -----------------------
    int abase3[3];
#pragma unroll
    for (int mt = 0; mt < 3; ++mt) {
        int m = mt * 16 + lm; if (m > 35) m = 35;
        int oy = m / 6, ox = m - 6 * oy;
        abase3[mt] = oy * ROW2 + ox * 20 + quad * 8;
    }
    f32x4 acc3[3][2] = {};
    {
        const unsigned short* wptr = wbuf3 + lane * 8;
        s16x8 wc0 = *(const s16x8*)(wptr);
        s16x8 wc1 = *(const s16x8*)(wptr + 512);
#pragma unroll
        for (int it = 0; it < 20; ++it) {
            s16x8 wn0 = *(const s16x8*)(wptr + (it + 1) * 1024);   // tail -> wband
            s16x8 wn1 = *(const s16x8*)(wptr + (it + 1) * 1024 + 512);
            const unsigned short* sb = h2w + (it >> 2) * ROW2 + (it & 3) * 32;
            s16x8 af[3];
#pragma unroll
            for (int mt = 0; mt < 3; ++mt)
                af[mt] = cat8(*(const s16x4*)(sb + abase3[mt]),
                              *(const s16x4*)(sb + abase3[mt] + 4));
            __builtin_amdgcn_s_setprio(1);
#pragma unroll
            for (int mt = 0; mt < 3; ++mt) {
                acc3[mt][0] = __builtin_amdgcn_mfma_f32_16x16x32_bf16(af[mt], wc0, acc3[mt][0], 0, 0, 0);
                acc3[mt][1] = __builtin_amdgcn_mfma_f32_16x16x32_bf16(af[mt], wc1, acc3[mt][1], 0, 0, 0);
            }
            __builtin_amdgcn_s_setprio(0);
            wc0 = wn0; wc1 = wn1;
        }
    }

    // ---- conv3 epilogue -> h3w[o*36+pos] (fp32, relu, overlays own h1) ----
    float* h3w = (float*)h1w;
#pragma unroll
    for (int mt = 0; mt < 3; ++mt) {
#pragma unroll
        for (int nt = 0; nt < 2; ++nt) {
            int o = nt * 16 + lm;
            if (o < 20) {
                float b3v = b3[o];
#pragma unroll
                for (int r = 0; r < 4; ++r) {
                    int pos = mt * 16 + quad * 4 + r;
                    if (pos < 36)
                        h3w[o * 36 + pos] = fmaxf(acc3[mt][nt][r] + b3v, 0.f);
                }
            }
        }
    }

    // ---- fc: coalesced global wf; single-wave reduce ----------------------
    float part[10];
#pragma unroll
    for (int n = 0; n < 10; ++n) part[n] = 0.f;
#pragma unroll 2
    for (int t = 0; t < 11; ++t) {                     // k = 0..703
        int k = t * 64 + lane;
        float v = h3w[k];
#pragma unroll
        for (int n = 0; n < 10; ++n)
            part[n] = fmaf(v, wf[n * 720 + k], part[n]);
    }
    {                                                  // tail k = 704..719
        int k = 704 + lane;
        if (lane < 16) {
            float v = h3w[k];
#pragma unroll
            for (int n = 0; n < 10; ++n)
                part[n] = fmaf(v, wf[n * 720 + k], part[n]);
        }
    }
#pragma unroll
    for (int n = 0; n < 10; ++n) {
#pragma unroll
        for (int off = 32; off >= 1; off >>= 1)
            part[n] += __shfl_xor(part[n], off, 64);
    }
    if (lane == 0) {
        float* dst = out + (size_t)img * 10;
#pragma unroll
        for (int n = 0; n < 10; ++n) dst[n] = part[n] + bf[n];
    }
}

extern "C" void kernel_launch(void* const* d_in, const int* in_sizes, int n_in,
                              void* d_out, int out_size, void* d_ws, size_t ws_size,
                              hipStream_t stream) {
    (void)n_in; (void)out_size; (void)ws_size;
    const float* x  = (const float*)d_in[0];
    const float* w1 = (const float*)d_in[1];
    const float* b1 = (const float*)d_in[2];
    const float* w2 = (const float*)d_in[3];
    const float* b2 = (const float*)d_in[4];
    const float* w3 = (const float*)d_in[5];
    const float* b3 = (const float*)d_in[6];
    const float* wf = (const float*)d_in[7];
    const float* bf = (const float*)d_in[8];
    float* out = (float*)d_out;

    const int B = in_sizes[0] / 784;                   // 4096

    unsigned short* wbuf = (unsigned short*)d_ws;      // 116736 bf16 = 228 KB

    wprep_k<<<456, 256, 0, stream>>>(w1, w2, w3, wbuf);
    fused_k<<<B / 2, 128, 0, stream>>>(x, b1, wbuf, wbuf + 40960, wbuf + 61440,
                                       b2, b3, wf, bf, out);
}